// Round 9
// baseline (418.293 us; speedup 1.0000x reference)
//
#include <hip/hip_runtime.h>

typedef __attribute__((ext_vector_type(8))) short short8;
typedef __attribute__((ext_vector_type(4))) float floatx4;

__device__ __forceinline__ float b2f(unsigned int u) { return __uint_as_float(u << 16); }
__device__ __forceinline__ unsigned short f2b(float f) {      // fp32 -> bf16 RNE
    unsigned int u = __float_as_uint(f);
    return (unsigned short)((u + 0x7fffu + ((u >> 16) & 1u)) >> 16);
}
__device__ __forceinline__ unsigned cvtpk(float lo, float hi) {  // 2xf32 -> packed bf16 (RNE)
    unsigned r;
    asm("v_cvt_pk_bf16_f32 %0, %1, %2" : "=v"(r) : "v"(lo), "v"(hi));
    return r;
}

#define EMB 128
#define NN  500000
#define BB  1024
#define NCT 9        // 8 feat col-tiles + 1 gate tile (col 128 = w_mask)
#define CH  8        // 16-row tiles per wave (amortizes the B register load)
#define WTB (4 * NCT * 512)   // wTf elements

// ---------------------------------------------------------------- init (+ inlined dtype detect)
// wTf fragment-major: wTf[((kk*NCT+ct)*64+lane)*8+j]
// = Blogical[n = ct*16 + (lane&15)][k = kk*32 + (lane>>4)*8 + j], where
// Blogical[n][k] = w_feat[k][n] (n<128), w_mask[k] (n==128), 0 else.
__global__ __launch_bounds__(256)
void kinit(float* __restrict__ denom, float* __restrict__ xg,
           unsigned short* __restrict__ wTf, const void* __restrict__ w_feat_,
           const void* __restrict__ w_mask_, const unsigned short* __restrict__ xr,
           const int* __restrict__ braw, int* __restrict__ flags, int N)
{
    __shared__ int sf32;
    int tid = threadIdx.x;
    if (tid < 64) {
        int good = 0;
#pragma unroll
        for (int j = 0; j < 4; ++j) {
            unsigned short u = xr[tid * 4 + j];
            unsigned e = (u >> 7) & 0xffu;
            if ((e >= 100u && e <= 140u) || u == 0) ++good;
        }
#pragma unroll
        for (int o = 1; o < 64; o <<= 1) good += __shfl_xor(good, o);
        if (tid == 0) {
            sf32 = (good < 240) ? 1 : 0;
            if (blockIdx.x == 0) {
                flags[0] = sf32;
                flags[1] = (braw[N - 1] == 0 && braw[N - 2] != 0) ? 1 : 0;
            }
        }
    }
    __syncthreads();
    bool f32 = sf32 != 0;

    int i = blockIdx.x * 256 + tid;
    if (i < BB) denom[i] = 0.f;
    if (i < BB * EMB) xg[i] = 0.f;
    if (i < WTB) {
        int blk = i >> 9, rem = i & 511;
        int lane = rem >> 3, j = rem & 7;
        int kk = blk / NCT, ct = blk - kk * NCT;
        int n = ct * 16 + (lane & 15);
        int k = kk * 32 + (lane >> 4) * 8 + j;
        unsigned short v = 0;
        if (n < 128)      v = f32 ? f2b(((const float*)w_feat_)[k * EMB + n])
                                  : ((const unsigned short*)w_feat_)[k * EMB + n];
        else if (n == 128) v = f32 ? f2b(((const float*)w_mask_)[k])
                                   : ((const unsigned short*)w_mask_)[k];
        wTf[i] = v;
    }
}

// ---------------------------------------------------------------- epilogue helpers
__device__ __forceinline__ void flush_racc(float (&racc)[8], int& runSeg,
                                           int quad, int l16, float* __restrict__ xg)
{
    if (runSeg >= 0) {
#pragma unroll
        for (int ct = 0; ct < 8; ++ct) {
            float p = racc[ct];
            p += __shfl_xor(p, 16);
            p += __shfl_xor(p, 32);
            if (quad == (ct & 3))
                atomicAdd(&xg[runSeg * EMB + ct * 16 + l16], p);
            racc[ct] = 0.f;
        }
    }
    runSeg = -1;
}

// ---------------------------------------------------------------- fused main, B-in-registers
// Each wave owns CH consecutive 16-row tiles. The ENTIRE B operand (36 KB =
// 36 fragments x 4 VGPRs = 144 regs) is loaded ONCE per wave into registers
// (static indexing only), so the MFMA chain has ZERO LDS reads and no lgkm
// waits -- MFMAs issue back-to-back. A is a one-shot 8-load burst per tile.
// LDS use is 256 B (gate exchange) -> occupancy is VGPR-bound: 2 waves/SIMD,
// which overlaps each burst's HBM wait with the sibling wave's compute.
// Softmax is shift-free (alpha invariant); denom via 16-lane segmented scan.
__global__ __launch_bounds__(256, 2)
void kmain(const void* __restrict__ x_, const int* __restrict__ braw,
           const void* __restrict__ bm_, const void* __restrict__ bf_,
           const unsigned short* __restrict__ wTf, const int* __restrict__ flags,
           float* __restrict__ denom, float* __restrict__ xg, int N)
{
    __shared__ float se[4][16];

    int tid = threadIdx.x;
    int wave = tid >> 6, lane = tid & 63;
    int quad = lane >> 4, l16 = lane & 15;
    bool f32  = flags[0] != 0;
    bool is64 = flags[1] != 0;

    int T = (N + 15) >> 4;
    int W = blockIdx.x * 4 + wave;
    int t0 = W * CH;
    int tend = t0 + CH; if (tend > T) tend = T;
    if (t0 >= tend) return;

    // ---- B operand into registers: 36 coalesced 1KB loads, once per wave
    short8 bfr[4][NCT];
#pragma unroll
    for (int kk = 0; kk < 4; ++kk)
#pragma unroll
        for (int ct = 0; ct < NCT; ++ct)
            bfr[kk][ct] = *(const short8*)(wTf + ((kk * NCT + ct) << 9) + (lane << 3));

    float bm = f32 ? ((const float*)bm_)[0]
                   : b2f((unsigned int)((const unsigned short*)bm_)[0]);
    float bfv[8];
#pragma unroll
    for (int ct = 0; ct < 8; ++ct)
        bfv[ct] = f32 ? ((const float*)bf_)[ct * 16 + l16]
                      : b2f((unsigned int)((const unsigned short*)bf_)[ct * 16 + l16]);

    const float* xf = (const float*)x_;
    const unsigned short* xu = (const unsigned short*)x_;
    float4 fz = make_float4(0.f, 0.f, 0.f, 0.f);
    short8 hz = {0, 0, 0, 0, 0, 0, 0, 0};

    float racc[8];
#pragma unroll
    for (int ct = 0; ct < 8; ++ct) racc[ct] = 0.f;
    int runSeg = -1;
    float* sew = se[wave];

    for (int t = t0; t < tend; ++t) {
        int n_ = (t << 4) + l16;

        // segment id for row l16 (issued alongside the x burst)
        int sv = -1;
        if (n_ < N) { int b_ = is64 ? braw[2 * n_] : braw[n_]; if (b_ >= 0 && b_ < BB) sv = b_; }

        // ---- one-shot A burst: 8 dwordx4 (f32) or 4 b128 (bf16)
        short8 afr[4];
        if (f32) {
            float4 av[8];
            const float* p = xf + (size_t)n_ * EMB + quad * 8;
#pragma unroll
            for (int kk = 0; kk < 4; ++kk) {
                av[kk * 2]     = (n_ < N) ? *(const float4*)(p + kk * 32)     : fz;
                av[kk * 2 + 1] = (n_ < N) ? *(const float4*)(p + kk * 32 + 4) : fz;
            }
#pragma unroll
            for (int kk = 0; kk < 4; ++kk) {
                float4 a = av[kk * 2], b = av[kk * 2 + 1];
                union { short8 s; unsigned u[4]; } cv;
                cv.u[0] = cvtpk(a.x, a.y); cv.u[1] = cvtpk(a.z, a.w);
                cv.u[2] = cvtpk(b.x, b.y); cv.u[3] = cvtpk(b.z, b.w);
                afr[kk] = cv.s;
            }
        } else {
            const unsigned short* p = xu + (size_t)n_ * EMB + quad * 8;
#pragma unroll
            for (int kk = 0; kk < 4; ++kk)
                afr[kk] = (n_ < N) ? *(const short8*)(p + kk * 32) : hz;
        }

        // ---- MFMA: all operands in registers, zero LDS on the chain
        floatx4 zero = {0.f, 0.f, 0.f, 0.f};
        floatx4 acc[NCT];
#pragma unroll
        for (int ct = 0; ct < NCT; ++ct) acc[ct] = zero;
#pragma unroll
        for (int kk = 0; kk < 4; ++kk)
#pragma unroll
            for (int ct = 0; ct < NCT; ++ct)
                acc[ct] = __builtin_amdgcn_mfma_f32_16x16x32_bf16(afr[kk], bfr[kk][ct], acc[ct], 0, 0, 0);

        // gate column (ct==8, col 128 lives in l16==0 lanes): row = quad*4 + r
        if (l16 == 0) {
#pragma unroll
            for (int r = 0; r < 4; ++r) sew[quad * 4 + r] = acc[8][r];
        }

        float g = sew[l16] + bm;
        float ev = (sv >= 0) ? __expf(fminf(g, 60.f)) : 0.f;

        // 16-element segmented scan (lanes 0..15) -> one atomicAdd(denom) per run
        if (lane < 16) {
            float v = ev;
#pragma unroll
            for (int o = 1; o < 16; o <<= 1) {
                float u  = __shfl_up(v, o);
                int   su = __shfl_up(sv, o);
                if (lane >= o && su == sv) v += u;
            }
            int sn = __shfl_down(sv, 1);
            if (sv >= 0 && (lane == 15 || sn != sv)) atomicAdd(&denom[sv], v);
        }

        float er[4];
#pragma unroll
        for (int r = 0; r < 4; ++r) er[r] = __shfl(ev, quad * 4 + r);

        int sF = __shfl(sv, 0), sL = __shfl(sv, 15);
        if (sF == sL) {
            if (sF >= 0) {
                if (sF != runSeg) { flush_racc(racc, runSeg, quad, l16, xg); runSeg = sF; }
#pragma unroll
                for (int ct = 0; ct < 8; ++ct) {
                    float p = 0.f;
#pragma unroll
                    for (int r = 0; r < 4; ++r) {
                        float v = acc[ct][r] + bfv[ct];
                        v = v >= 0.f ? v : 0.01f * v;
                        p += v * er[r];
                    }
                    racc[ct] += p;
                }
            }
        } else {
            flush_racc(racc, runSeg, quad, l16, xg);
            int sr[4];
#pragma unroll
            for (int r = 0; r < 4; ++r) sr[r] = __shfl(sv, quad * 4 + r);
#pragma unroll
            for (int ct = 0; ct < 8; ++ct) {
                int col = ct * 16 + l16;
                float a = 0.f; int cur = -1;
#pragma unroll
                for (int r = 0; r < 4; ++r) {
                    int s = sr[r];
                    float v = acc[ct][r] + bfv[ct];
                    v = v >= 0.f ? v : 0.01f * v;
                    v *= er[r];
                    if (s != cur) {
                        if (cur >= 0) atomicAdd(&xg[cur * EMB + col], a);
                        a = 0.f; cur = s;
                    }
                    if (s >= 0) a += v;
                }
                if (cur >= 0) atomicAdd(&xg[cur * EMB + col], a);
            }
        }
    }

    flush_racc(racc, runSeg, quad, l16, xg);
}

// ---------------------------------------------------------------- final: normalize + linear + leaky + residual
__global__ __launch_bounds__(128)
void kfinal(const float* __restrict__ xg, const float* __restrict__ denom,
            const void* __restrict__ xg_old_, const void* __restrict__ w_tr_,
            const void* __restrict__ b_tr_, const int* __restrict__ flags,
            void* __restrict__ out_)
{
    __shared__ float cat[2 * EMB];
    int b = blockIdx.x, j = threadIdx.x;
    bool f32 = flags[0] != 0;

    float d = denom[b];
    float xgv = xg[b * EMB + j];
    xgv = (d > 0.f) ? xgv / d : 0.f;
    if (xgv != xgv) xgv = 700.0f;                 // sentinel: NaN escaped kmain
    cat[j] = xgv;
    float old = f32 ? ((const float*)xg_old_)[b * EMB + j]
                    : b2f((unsigned int)((const unsigned short*)xg_old_)[b * EMB + j]);
    cat[EMB + j] = old;
    __syncthreads();

    float acc = f32 ? ((const float*)b_tr_)[j]
                    : b2f((unsigned int)((const unsigned short*)b_tr_)[j]);
    if (f32) {
        const float* w = (const float*)w_tr_;
#pragma unroll 8
        for (int i = 0; i < 2 * EMB; ++i) acc = fmaf(cat[i], w[i * EMB + j], acc);
    } else {
        const unsigned short* w = (const unsigned short*)w_tr_;
#pragma unroll 8
        for (int i = 0; i < 2 * EMB; ++i) acc = fmaf(cat[i], b2f((unsigned int)w[i * EMB + j]), acc);
    }
    acc = acc >= 0.f ? acc : 0.01f * acc;
    acc += old;
    if (acc != acc) acc = 300.0f;                 // sentinel: NaN in kfinal inputs

    if (f32) ((float*)out_)[b * EMB + j] = acc;
    else     ((unsigned short*)out_)[b * EMB + j] = f2b(acc);
}

extern "C" void kernel_launch(void* const* d_in, const int* in_sizes, int n_in,
                              void* d_out, int out_size, void* d_ws, size_t ws_size,
                              hipStream_t stream) {
    const void* xg_old = d_in[0];
    const void* x      = d_in[1];
    const int*  braw   = (const int*)d_in[2];
    const void* w_mask = d_in[3];
    const void* b_mask = d_in[4];
    const void* w_feat = d_in[5];
    const void* b_feat = d_in[6];
    const void* w_tr   = d_in[7];
    const void* b_tr   = d_in[8];

    const int N = NN;

    char* ws = (char*)d_ws;
    size_t off = 0;
    int*   flags = (int*)(ws + off);   off += 64;
    float* denom = (float*)(ws + off); off += (size_t)BB * 4;
    float* xg    = (float*)(ws + off); off += (size_t)BB * EMB * 4;
    unsigned short* wTf = (unsigned short*)(ws + off); off += (size_t)WTB * 2;

    int T = (N + 15) >> 4;
    int nblk = (T + 4 * CH - 1) / (4 * CH);   // 977
    kinit<<<(BB * EMB + 255) / 256, 256, 0, stream>>>(denom, xg, wTf, w_feat, w_mask,
                                                      (const unsigned short*)x, braw, flags, N);
    kmain<<<nblk, 256, 0, stream>>>(x, braw, b_mask, b_feat, wTf,
                                    flags, denom, xg, N);
    kfinal<<<BB, 128, 0, stream>>>(xg, denom, xg_old, w_tr, b_tr, flags, d_out);
}